// Round 7
// baseline (203.257 us; speedup 1.0000x reference)
//
#include <hip/hip_runtime.h>
#include <math.h>

typedef _Float16 half8_t  __attribute__((ext_vector_type(8)));
typedef _Float16 half4_t  __attribute__((ext_vector_type(4)));
typedef float    floatx16 __attribute__((ext_vector_type(16)));

#define BS   16
#define LL   2048
#define DIMC 512
#define NG   2
#define VD   256
#define NC   320
#define NELEM ((double)(VD*LL))   // 524288 per (b,g)

// global -> LDS direct DMA, 16 B per lane. gsrc per-lane, ldst wave-uniform.
#define GLL(gsrc, ldst) __builtin_amdgcn_global_load_lds( \
    (const __attribute__((address_space(1))) unsigned int*)(gsrc), \
    (__attribute__((address_space(3))) unsigned int*)(ldst), 16, 0, 0)

// ---------------------------------------------------------------------------
// k_proj (fused): blocks 0..511 = projection tiles; blocks 512..551 = aux
// (build Eimg f16 hi/lo chunk-image of 64*E for k_vq's GLL staging; blocks
// 512/513 also compute e2f[c] = 64*||E_c||^2 in fp64).
//
// Projection: ze = X * (16W)^T / 16 via 3-term f16-split mfma_32x32x16_f16.
// Tile 128 pos x 256 outdim. W split INLINE from raw fp32 (L2-resident; no
// prep kernel, no Wimg). Per-block fp64 sum/sumsq -> pstats[blk] (private
// slot, no memset, no atomics, deterministic).
// LDS: Ah 18432 + Bh 36864 + red 64 = 55360 B -> 2 blocks/CU.
// ---------------------------------------------------------------------------
__global__ __launch_bounds__(256, 2) void k_proj(
    const float* __restrict__ x, const float* __restrict__ W,
    const float* __restrict__ emb,
    float* __restrict__ ze, double* __restrict__ pstats,
    _Float16* __restrict__ Eimg, float* __restrict__ e2f)
{
  __shared__ _Float16 Ah[128][72];
  __shared__ _Float16 Bh[256 * 72];
  __shared__ double red[8];

  const int blk = blockIdx.x;
  const int t  = threadIdx.x;

  if (blk >= 512) {
    // ---- aux: E chunk-image split (+ e2f on blocks 512/513) ----
    int base = ((blk - 512) * 256 + t) * 8;   // flat (code,v), 8 contiguous
    int k = base & 255, c = k >> 5, kk = k & 31;
    int code = base >> 8;
    float4 v0 = *(const float4*)(emb + base);
    float4 v1 = *(const float4*)(emb + base + 4);
    float vv[8] = {v0.x, v0.y, v0.z, v0.w, v1.x, v1.y, v1.z, v1.w};
    half8_t hh, ll;
    #pragma unroll
    for (int i = 0; i < 8; ++i) {
      float s = vv[i] * 64.0f;
      _Float16 h = (_Float16)s;
      hh[i] = h; ll[i] = (_Float16)(s - (float)h);
    }
    size_t rb = ((size_t)c * 320 + code) * 72;
    *(half8_t*)&Eimg[rb + kk]      = hh;
    *(half8_t*)&Eimg[rb + 32 + kk] = ll;
    if (blk < 514) {
      int cd = (blk - 512) * 256 + t;
      if (cd < NC) {
        const float* er = emb + (size_t)cd * VD;
        double s[4] = {0.0, 0.0, 0.0, 0.0};
        for (int v = 0; v < VD; v += 16)
          #pragma unroll
          for (int u = 0; u < 4; ++u) {
            float4 e4 = *(const float4*)(er + v + u * 4);
            s[u] += (double)e4.x * e4.x + (double)e4.y * e4.y
                  + (double)e4.z * e4.z + (double)e4.w * e4.w;
          }
        e2f[cd] = (float)(64.0 * (s[0] + s[1] + s[2] + s[3]));
      }
    }
    return;
  }

  // ---- projection ----
  const int g  = blk & 1;
  const int m0 = (blk >> 1) * 128;     // flat position b*2048+l
  const int lane = t & 63, w = t >> 6;
  const int col  = lane & 31, hq = lane >> 5;
  const int mw = (w & 1) * 64, nw = (w >> 1) * 128;

  floatx16 acc[2][4];
  #pragma unroll
  for (int i = 0; i < 2; ++i)
    #pragma unroll
    for (int j = 0; j < 4; ++j)
      #pragma unroll
      for (int e = 0; e < 16; ++e) acc[i][j][e] = 0.f;

  for (int c = 0; c < 8; ++c) {
    // X chunk: 128 rows x 32 k, split to hi/lo
    #pragma unroll
    for (int i = 0; i < 4; ++i) {
      int idx = i * 256 + t;
      int row = idx >> 3, kq = idx & 7;
      float4 v = *(const float4*)(x + ((size_t)(m0 + row)) * DIMC + g * VD + c * 32 + kq * 4);
      half4_t hh, ll;
      { _Float16 h = (_Float16)v.x; hh[0] = h; ll[0] = (_Float16)(v.x - (float)h); }
      { _Float16 h = (_Float16)v.y; hh[1] = h; ll[1] = (_Float16)(v.y - (float)h); }
      { _Float16 h = (_Float16)v.z; hh[2] = h; ll[2] = (_Float16)(v.z - (float)h); }
      { _Float16 h = (_Float16)v.w; hh[3] = h; ll[3] = (_Float16)(v.w - (float)h); }
      *(half4_t*)&Ah[row][kq * 4]      = hh;
      *(half4_t*)&Ah[row][32 + kq * 4] = ll;
    }
    // W chunk: 256 rows x 32 k, inline split from raw fp32 (coalesced)
    #pragma unroll
    for (int i = 0; i < 4; ++i) {
      int idx = i * 256 + t;
      int row = idx >> 2, q = idx & 3;
      const float* wp = W + ((size_t)(g * VD + row)) * VD + c * 32 + q * 8;
      float4 v0 = *(const float4*)(wp);
      float4 v1 = *(const float4*)(wp + 4);
      float vv[8] = {v0.x, v0.y, v0.z, v0.w, v1.x, v1.y, v1.z, v1.w};
      half8_t hh, ll;
      #pragma unroll
      for (int u = 0; u < 8; ++u) {
        float s = vv[u] * 16.0f;
        _Float16 h = (_Float16)s;
        hh[u] = h; ll[u] = (_Float16)(s - (float)h);
      }
      *(half8_t*)&Bh[row * 72 + q * 8]      = hh;
      *(half8_t*)&Bh[row * 72 + 32 + q * 8] = ll;
    }
    __syncthreads();
    #pragma unroll
    for (int ks = 0; ks < 2; ++ks) {
      const int ko = ks * 16 + hq * 8;
      half8_t azh[2], azl[2], bwh[4], bwl[4];
      #pragma unroll
      for (int i = 0; i < 2; ++i) {
        azh[i] = *(const half8_t*)&Ah[mw + i * 32 + col][ko];
        azl[i] = *(const half8_t*)&Ah[mw + i * 32 + col][32 + ko];
      }
      #pragma unroll
      for (int j = 0; j < 4; ++j) {
        bwh[j] = *(const half8_t*)&Bh[(nw + j * 32 + col) * 72 + ko];
        bwl[j] = *(const half8_t*)&Bh[(nw + j * 32 + col) * 72 + 32 + ko];
      }
      #pragma unroll
      for (int mi = 0; mi < 2; ++mi)
        #pragma unroll
        for (int ni = 0; ni < 4; ++ni) {
          acc[mi][ni] = __builtin_amdgcn_mfma_f32_32x32x16_f16(azh[mi], bwh[ni], acc[mi][ni], 0, 0, 0);
          acc[mi][ni] = __builtin_amdgcn_mfma_f32_32x32x16_f16(azh[mi], bwl[ni], acc[mi][ni], 0, 0, 0);
          acc[mi][ni] = __builtin_amdgcn_mfma_f32_32x32x16_f16(azl[mi], bwh[ni], acc[mi][ni], 0, 0, 0);
        }
    }
    __syncthreads();
  }

  // epilogue: scale back 1/16 (exact), fp64 stats, stores
  double s1 = 0.0, s2 = 0.0;
  #pragma unroll
  for (int mi = 0; mi < 2; ++mi)
    #pragma unroll
    for (int ni = 0; ni < 4; ++ni)
      #pragma unroll
      for (int r = 0; r < 16; ++r) {
        float vv = acc[mi][ni][r] * 0.0625f;
        double d = (double)vv; s1 += d; s2 += d * d;
        int ml = mw + mi * 32 + (r & 3) + 8 * (r >> 2) + 4 * hq;
        int nl = nw + ni * 32 + col;
        ze[((size_t)(m0 + ml)) * DIMC + g * VD + nl] = vv;
      }
  #pragma unroll
  for (int off = 32; off > 0; off >>= 1) {
    s1 += __shfl_down(s1, off);
    s2 += __shfl_down(s2, off);
  }
  if (lane == 0) { red[w * 2] = s1; red[w * 2 + 1] = s2; }
  __syncthreads();
  if (t == 0) {
    pstats[blk * 2 + 0] = red[0] + red[2] + red[4] + red[6];
    pstats[blk * 2 + 1] = red[1] + red[3] + red[5] + red[7];
  }
}

// ---------------------------------------------------------------------------
// k_vq: reduce pstats (16 fixed-order fp64 partials) -> mean/rstd; GroupNorm
// -> split -> flipped MFMA (A = E' codes, B = Z positions): D[code][pos],
// col=lane = pos -> in-lane argmin over 160 codes + one shfl_xor(32).
// Tile 128 pos x 320 codes; E' chunks staged via global_load_lds from Eimg.
// Epilogue: out rows = emb[idx] (STE residue ~1e-7 << bf16 comparison floor).
// ---------------------------------------------------------------------------
__global__ __launch_bounds__(256, 2) void k_vq(
    float* __restrict__ zio, const float* __restrict__ emb,
    const _Float16* __restrict__ Eimg,
    const float* __restrict__ gnw, const float* __restrict__ gnb,
    const double* __restrict__ pstats, const float* __restrict__ e2f)
{
  __shared__ _Float16 Zs[128][72];
  __shared__ _Float16 Es[320 * 72];
  __shared__ float e2sh[NC];
  __shared__ int idxs[128];

  const int blk = blockIdx.x;
  const int g  = blk & 1;
  const int m0 = (blk >> 1) * 128;
  const int b  = m0 >> 11;
  const int t  = threadIdx.x;
  const int lane = t & 63, w = t >> 6;
  const int col  = lane & 31, hq = lane >> 5;

  // reduce this (b,g)'s 16 partials in fixed order (deterministic, uniform)
  double ss1 = 0.0, ss2 = 0.0;
  #pragma unroll 4
  for (int j = 0; j < 16; ++j) {
    int pb = (((b * 16 + j) << 1) | g) * 2;
    ss1 += pstats[pb]; ss2 += pstats[pb + 1];
  }
  double mu = ss1 / NELEM, var = ss2 / NELEM - mu * mu;
  const float mean = (float)mu;
  const float rstd = (float)(1.0 / sqrt(var + 1e-5));

  for (int c = t; c < NC; c += 256) e2sh[c] = e2f[c];

  float* zbase = zio + (size_t)m0 * DIMC + g * VD;
  const float* gw = gnw + g * VD;
  const float* gb = gnb + g * VD;

  floatx16 acc[10];
  #pragma unroll
  for (int i = 0; i < 10; ++i)
    #pragma unroll
    for (int e = 0; e < 16; ++e) acc[i][e] = 0.f;

  for (int c = 0; c < 8; ++c) {
    // Z chunk: 128 rows x 32 k, GroupNorm + split
    #pragma unroll
    for (int i = 0; i < 4; ++i) {
      int idx = i * 256 + t;
      int row = idx >> 3, kq = idx & 7;
      float4 v  = *(const float4*)(zbase + (size_t)row * DIMC + c * 32 + kq * 4);
      float4 w4 = *(const float4*)(gw + c * 32 + kq * 4);
      float4 b4 = *(const float4*)(gb + c * 32 + kq * 4);
      float zn0 = (v.x - mean) * rstd * w4.x + b4.x;
      float zn1 = (v.y - mean) * rstd * w4.y + b4.y;
      float zn2 = (v.z - mean) * rstd * w4.z + b4.z;
      float zn3 = (v.w - mean) * rstd * w4.w + b4.w;
      half4_t hh, ll;
      { _Float16 h = (_Float16)zn0; hh[0] = h; ll[0] = (_Float16)(zn0 - (float)h); }
      { _Float16 h = (_Float16)zn1; hh[1] = h; ll[1] = (_Float16)(zn1 - (float)h); }
      { _Float16 h = (_Float16)zn2; hh[2] = h; ll[2] = (_Float16)(zn2 - (float)h); }
      { _Float16 h = (_Float16)zn3; hh[3] = h; ll[3] = (_Float16)(zn3 - (float)h); }
      *(half4_t*)&Zs[row][kq * 4]      = hh;
      *(half4_t*)&Zs[row][32 + kq * 4] = ll;
    }
    // E' chunk image: 46080 B via global_load_lds (45 wave-loads over 4 waves)
    {
      const char* ec = (const char*)Eimg + (size_t)c * 320 * 144;
      for (int i = w; i < 45; i += 4) {
        int off = i * 1024 + lane * 16;
        GLL(ec + off, (char*)Es + off);
      }
    }
    __syncthreads();
    #pragma unroll
    for (int ks = 0; ks < 2; ++ks) {
      const int ko = ks * 16 + hq * 8;
      half8_t bzh = *(const half8_t*)&Zs[w * 32 + col][ko];
      half8_t bzl = *(const half8_t*)&Zs[w * 32 + col][32 + ko];
      #pragma unroll
      for (int mt = 0; mt < 10; ++mt) {
        half8_t aeh = *(const half8_t*)&Es[(mt * 32 + col) * 72 + ko];
        half8_t ael = *(const half8_t*)&Es[(mt * 32 + col) * 72 + 32 + ko];
        acc[mt] = __builtin_amdgcn_mfma_f32_32x32x16_f16(aeh, bzh, acc[mt], 0, 0, 0);
        acc[mt] = __builtin_amdgcn_mfma_f32_32x32x16_f16(aeh, bzl, acc[mt], 0, 0, 0);
        acc[mt] = __builtin_amdgcn_mfma_f32_32x32x16_f16(ael, bzh, acc[mt], 0, 0, 0);
      }
    }
    __syncthreads();
  }

  // in-lane argmin over 160 codes (lexicographic (d, code) = first-min), then
  // combine the hq pair with shfl_xor(32). Lane col of wave w owns pos w*32+col.
  float bv = 3.4e38f; int bi = 0x7fffffff;
  #pragma unroll
  for (int mt = 0; mt < 10; ++mt)
    #pragma unroll
    for (int r = 0; r < 16; ++r) {
      int code = mt * 32 + (r & 3) + 8 * (r >> 2) + 4 * hq;
      float d = e2sh[code] - 2.0f * acc[mt][r];
      if (d < bv || (d == bv && code < bi)) { bv = d; bi = code; }
    }
  {
    float ov = __shfl_xor(bv, 32);
    int   oi = __shfl_xor(bi, 32);
    if (ov < bv || (ov == bv && oi < bi)) { bv = ov; bi = oi; }
  }
  if (hq == 0) idxs[w * 32 + col] = bi;
  __syncthreads();

  // epilogue: out rows = emb[idx] (pure gather, no ze re-read)
  #pragma unroll
  for (int it = 0; it < 32; ++it) {
    int idx = it * 256 + t;             // 0..8191
    int row = idx >> 6, q4 = (idx & 63) * 4;
    int id = idxs[row];
    float4 e4 = *(const float4*)(emb + (size_t)id * VD + q4);
    *(float4*)(zbase + (size_t)row * DIMC + q4) = e4;
  }
}

extern "C" void kernel_launch(void* const* d_in, const int* in_sizes, int n_in,
                              void* d_out, int out_size, void* d_ws, size_t ws_size,
                              hipStream_t stream) {
  const float* x   = (const float*)d_in[0];
  const float* W   = (const float*)d_in[1];   // (2,256,256)
  const float* gnw = (const float*)d_in[2];   // (512,)
  const float* gnb = (const float*)d_in[3];   // (512,)
  const float* emb = (const float*)d_in[4];   // (320,1,256)
  float* out = (float*)d_out;

  double*   pstats = (double*)d_ws;                      // 512*2*8 = 8192 B
  float*    e2f    = (float*)((char*)d_ws + 8192);       // 1280 B
  _Float16* Eimg   = (_Float16*)((char*)d_ws + 16384);   // 368640 B -> 385 KB

  k_proj<<<552, 256, 0, stream>>>(x, W, emb, out, pstats, Eimg, e2f);
  k_vq<<<512, 256, 0, stream>>>(out, emb, Eimg, gnw, gnb, pstats, e2f);
}